// Round 9
// baseline (613.234 us; speedup 1.0000x reference)
//
#include <hip/hip_runtime.h>
#include <stdint.h>

#define BR 262144
#define NTAB 17
#define MAXR 512
#define DIN 272
#define AS0 296   // LDS row stride (bf16) layer0 (K padded to 288); also C-restage stride
#define ASM 264   // LDS row stride (bf16) mid layers (K=256); also C-restage stride
#define NCOPY 32
#define BNEPS 1e-5f

typedef __attribute__((ext_vector_type(8))) short short8;
typedef __attribute__((ext_vector_type(4))) float f32x4;
typedef __attribute__((ext_vector_type(4))) unsigned short ushort4w;

__device__ __forceinline__ unsigned short f2bf(float f) {
  union { float f; unsigned u; } v; v.f = f;
  return (unsigned short)((v.u + 0x7FFFu + ((v.u >> 16) & 1u)) >> 16);
}
__device__ __forceinline__ float bf2f(unsigned short h) {
  union { unsigned u; float f; } v; v.u = ((unsigned)h) << 16;
  return v.f;
}

// ---------- prep: tables f32 -> bf16; pack W0 -> MFMA B-frags; zero stats ----------
__global__ void k_prep0(const float* __restrict__ W0, const float* __restrict__ tables,
                        unsigned short* __restrict__ pW0, unsigned short* __restrict__ tb,
                        float* __restrict__ stats) {
  int tid = blockIdx.x * blockDim.x + threadIdx.x;
  int nth = gridDim.x * blockDim.x;
  for (int i = tid; i < NCOPY * 1280; i += nth) stats[i] = 0.f;
  for (int e = tid; e < 17408; e += nth) {
    const float* src = tables + (size_t)e * 8;
    f32x4 v0 = ((const f32x4*)src)[0];
    f32x4 v1 = ((const f32x4*)src)[1];
    unsigned short tmp[8];
#pragma unroll
    for (int j = 0; j < 4; j++) { tmp[j] = f2bf(v0[j]); tmp[4 + j] = f2bf(v1[j]); }
    *(short8*)&tb[(size_t)e * 8] = *(short8*)tmp;
  }
  for (int e = tid; e < 9 * 16 * 64; e += nth) {
    int l = e & 63, f = e >> 6;
    int nf = f & 15, ks = f >> 4;
    int col = nf * 16 + (l & 15);
    int kb = ks * 32 + ((l >> 4) << 3);
    unsigned short tmp[8];
#pragma unroll
    for (int j = 0; j < 8; j++) {
      int k = kb + j;
      tmp[j] = f2bf(k < DIN ? W0[k * 256 + col] : 0.f);
    }
    *(short8*)&pW0[(size_t)e * 8] = *(short8*)tmp;
  }
}

// ---------- fold BN(layer l) into W(l+1) ----------
template <int KP, int NP>
__global__ void k_fold(const float* __restrict__ stats, int offSum, int offSq,
                       const float* __restrict__ g, const float* __restrict__ be,
                       const float* __restrict__ W, const float* __restrict__ b,
                       unsigned short* __restrict__ pW, float* __restrict__ bOut) {
  __shared__ float sa[KP], sc[KP];
  int tid = threadIdx.x;  // 256
  if (tid < KP) {
    float s = 0.f, q = 0.f;
    for (int c = 0; c < NCOPY; c++) {
      s += stats[c * 1280 + offSum + tid];
      q += stats[c * 1280 + offSq + tid];
    }
    float mu = s * (1.f / BR);
    float var = fmaxf(q * (1.f / BR) - mu * mu, 0.f);
    float a = g[tid] * rsqrtf(var + BNEPS);
    sa[tid] = a;
    sc[tid] = be[tid] - mu * a;
  }
  __syncthreads();
  const int NFT = NP / 16;
  const int ENT = (KP / 32) * NFT * 64;
  for (int e = blockIdx.x * blockDim.x + tid; e < ENT; e += gridDim.x * blockDim.x) {
    int l = e & 63, f = e >> 6;
    int nf = f % NFT, ks = f / NFT;
    int col = nf * 16 + (l & 15);
    int kb = ks * 32 + ((l >> 4) << 3);
    unsigned short tmp[8];
#pragma unroll
    for (int j = 0; j < 8; j++) {
      int k = kb + j;
      tmp[j] = f2bf(sa[k] * W[k * NP + col]);
    }
    *(short8*)&pW[(size_t)e * 8] = *(short8*)tmp;
  }
  if (blockIdx.x == 0 && tid < NP) {
    float s = b[tid];
    for (int k = 0; k < KP; k++) s += sc[k] * W[k * NP + tid];
    bOut[tid] = s;
  }
}

// ---------- fold BN(layer2) into Wout ----------
__global__ void k_foldout(const float* __restrict__ stats, int offSum, int offSq,
                          const float* __restrict__ g, const float* __restrict__ be,
                          const float* __restrict__ Wout, const float* __restrict__ bout,
                          float* __restrict__ woutp, float* __restrict__ boutp) {
  __shared__ float red[128];
  int tid = threadIdx.x;  // 128 threads
  float s = 0.f, q = 0.f;
  for (int c = 0; c < NCOPY; c++) {
    s += stats[c * 1280 + offSum + tid];
    q += stats[c * 1280 + offSq + tid];
  }
  float mu = s * (1.f / BR);
  float var = fmaxf(q * (1.f / BR) - mu * mu, 0.f);
  float a = g[tid] * rsqrtf(var + BNEPS);
  float c = be[tid] - mu * a;
  float w = Wout[tid];
  woutp[tid] = a * w;
  red[tid] = c * w;
  __syncthreads();
  for (int st = 64; st > 0; st >>= 1) {
    if (tid < st) red[tid] += red[tid + st];
    __syncthreads();
  }
  if (tid == 0) boutp[0] = red[0] + bout[0];
}

// ---------- shared GEMM body (R4-verified) ----------
template <int KSTEPS, int N, int AST, int MF>
__device__ __forceinline__ void gemm_body(unsigned short* As, const unsigned short* __restrict__ pW,
                                          const float* __restrict__ bias, unsigned short* __restrict__ Y,
                                          int brow, float* ssum, float* ssq,
                                          float* __restrict__ gsum, float* __restrict__ gsq) {
  const int tid = threadIdx.x;
  const int lane = tid & 63, wave = tid >> 6;
  constexpr int WC = N / 64;
  const int wc = wave % WC, wr = wave / WC;
  const int wrow = wr * (MF * 16);
  const int wcolf = wc * 4;
  const int arow = lane & 15;
  const int koff = (lane >> 4) << 3;
  const int grp = lane >> 4;

  f32x4 zero4 = {0.f, 0.f, 0.f, 0.f};
  f32x4 acc[MF][4];
#pragma unroll
  for (int mf = 0; mf < MF; mf++)
#pragma unroll
    for (int nf = 0; nf < 4; nf++) acc[mf][nf] = zero4;

  short8 bcur[4], bnxt[4];
#pragma unroll
  for (int nf = 0; nf < 4; nf++)
    bcur[nf] = *(const short8*)&pW[(size_t)((wcolf + nf) * 64 + lane) * 8];

#pragma unroll
  for (int ks = 0; ks < KSTEPS; ks++) {
    if (ks + 1 < KSTEPS) {
#pragma unroll
      for (int nf = 0; nf < 4; nf++)
        bnxt[nf] = *(const short8*)&pW[(size_t)(((ks + 1) * (N / 16) + wcolf + nf) * 64 + lane) * 8];
    }
#pragma unroll
    for (int mf = 0; mf < MF; mf++) {
      short8 am = *(const short8*)&As[(wrow + mf * 16 + arow) * AST + ks * 32 + koff];
#pragma unroll
      for (int nf = 0; nf < 4; nf++)
        acc[mf][nf] = __builtin_amdgcn_mfma_f32_16x16x32_bf16(bcur[nf], am, acc[mf][nf], 0, 0, 0);
    }
#pragma unroll
    for (int nf = 0; nf < 4; nf++) bcur[nf] = bnxt[nf];
  }

  __syncthreads();

#pragma unroll
  for (int nf = 0; nf < 4; nf++) {
    const int c0 = (wcolf + nf) * 16 + grp * 4;
    f32x4 bb = *(const f32x4*)&bias[c0];
    float s[4] = {0.f, 0.f, 0.f, 0.f}, q[4] = {0.f, 0.f, 0.f, 0.f};
#pragma unroll
    for (int mf = 0; mf < MF; mf++) {
      const int r = wrow + mf * 16 + arow;
      unsigned short o[4];
#pragma unroll
      for (int j = 0; j < 4; j++) {
        float v = fmaxf(acc[mf][nf][j] + bb[j], 0.f);
        o[j] = f2bf(v);
        s[j] += v;
        q[j] += v * v;
      }
      *(ushort4w*)&As[r * AST + c0] = *(ushort4w*)o;
    }
#pragma unroll
    for (int d = 1; d < 16; d <<= 1) {
#pragma unroll
      for (int j = 0; j < 4; j++) {
        s[j] += __shfl_xor(s[j], d, 64);
        q[j] += __shfl_xor(q[j], d, 64);
      }
    }
    if ((lane & 15) == 0) {
#pragma unroll
      for (int j = 0; j < 4; j++) {
        atomicAdd(&ssum[c0 + j], s[j]);
        atomicAdd(&ssq[c0 + j], q[j]);
      }
    }
  }
  __syncthreads();

  constexpr int CH = N / 8;
  for (int i = tid; i < 64 * CH; i += 256) {
    int row = i / CH, ch = i % CH;
    *(short8*)&Y[(size_t)(brow + row) * 256 + ch * 8] = *(const short8*)&As[row * AST + ch * 8];
  }
  if (tid < N) {
    atomicAdd(&gsum[tid], ssum[tid]);
    atomicAdd(&gsq[tid], ssq[tid]);
  }
}

// ---------- layer 0: embedding gather (bf16 tables, LDS-staged indices) + GEMM ----------
__global__ __launch_bounds__(256, 3) void k_gemm0(const int* __restrict__ x, const unsigned short* __restrict__ tb,
                        const unsigned short* __restrict__ pW, const float* __restrict__ bias,
                        unsigned short* __restrict__ Y, float* __restrict__ stats, int offSum, int offSq) {
  __shared__ unsigned short As[64 * AS0];
  __shared__ int sx[64 * NTAB];
  __shared__ float ssum[256], ssq[256];
  const int tid = threadIdx.x;
  if (tid < 256) { ssum[tid] = 0.f; ssq[tid] = 0.f; }
  const int brow = blockIdx.x * 64;
  for (int t = tid; t < 64 * NTAB; t += 256) sx[t] = x[brow * NTAB + t];
  short8 z8 = {0, 0, 0, 0, 0, 0, 0, 0};
  for (int t = tid; t < 64; t += 256) {
    *(short8*)&As[t * AS0 + 272] = z8;
    *(short8*)&As[t * AS0 + 280] = z8;
    *(short8*)&As[t * AS0 + 288] = z8;
  }
  __syncthreads();
  for (int i = tid; i < 64 * NTAB * 2; i += 256) {
    int r = i / (NTAB * 2);
    int rem = i - r * (NTAB * 2);
    int tbl = rem >> 1, half = rem & 1;
    int idx = sx[r * NTAB + tbl];
    short8 v = *(const short8*)&tb[((size_t)(tbl * MAXR + idx)) * 16 + half * 8];
    *(short8*)&As[r * AS0 + tbl * 16 + half * 8] = v;
  }
  __syncthreads();
  float* gsum = stats + (size_t)(blockIdx.x & (NCOPY - 1)) * 1280 + offSum;
  float* gsq  = stats + (size_t)(blockIdx.x & (NCOPY - 1)) * 1280 + offSq;
  gemm_body<9, 256, AS0, 4>(As, pW, bias, Y, brow, ssum, ssq, gsum, gsq);
}

// ---------- mid layers ----------
template <int N, int MF>
__global__ __launch_bounds__(256, 3) void k_gemm_mid(const unsigned short* __restrict__ Yin,
                           const unsigned short* __restrict__ pW, const float* __restrict__ bias,
                           unsigned short* __restrict__ Y, float* __restrict__ stats, int offSum, int offSq) {
  __shared__ unsigned short As[64 * ASM];
  __shared__ float ssum[256], ssq[256];
  const int tid = threadIdx.x;
  if (tid < 256) { ssum[tid] = 0.f; ssq[tid] = 0.f; }
  const int brow = blockIdx.x * 64;
  for (int i = tid; i < 64 * 32; i += 256) {
    int row = i >> 5, c16 = i & 31;
    short8 v = *(const short8*)&Yin[((size_t)(brow + row)) * 256 + c16 * 8];
    *(short8*)&As[row * ASM + c16 * 8] = v;
  }
  __syncthreads();
  float* gsum = stats + (size_t)(blockIdx.x & (NCOPY - 1)) * 1280 + offSum;
  float* gsq  = stats + (size_t)(blockIdx.x & (NCOPY - 1)) * 1280 + offSq;
  gemm_body<8, N, ASM, MF>(As, pW, bias, Y, brow, ssum, ssq, gsum, gsq);
}

// ---------- final dot ----------
__global__ void k_out(const unsigned short* __restrict__ Y, const float* __restrict__ woutp,
                      const float* __restrict__ boutp, float* __restrict__ out) {
  __shared__ float w[128];
  const int tid = threadIdx.x;
  if (tid < 128) w[tid] = woutp[tid];
  __syncthreads();
  const int lane = tid & 63, wave = tid >> 6;
  const int sub = lane & 7, rloc = lane >> 3;
  const int row = blockIdx.x * 32 + wave * 8 + rloc;
  const unsigned short* yr = &Y[(size_t)row * 256 + sub * 16];
  short8 v0 = *(const short8*)yr;
  short8 v1 = *(const short8*)(yr + 8);
  float acc = 0.f;
#pragma unroll
  for (int j = 0; j < 8; j++) acc += bf2f((unsigned short)v0[j]) * w[sub * 16 + j];
#pragma unroll
  for (int j = 0; j < 8; j++) acc += bf2f((unsigned short)v1[j]) * w[sub * 16 + 8 + j];
  acc += __shfl_xor(acc, 1, 64);
  acc += __shfl_xor(acc, 2, 64);
  acc += __shfl_xor(acc, 4, 64);
  if (sub == 0) out[row] = acc + boutp[0];
}

// ---------- DIAGNOSTIC probes: ablation of mid-layer phases (run AFTER k_out; Y is dead) ----------
// MODE 0: full replica. MODE 1: staging + K-loop only. MODE 2: staging + epilogue only.
// 2 tiles per block (grid 2048) so all probes rank in the top-5 table.
template <int MODE>
__global__ __launch_bounds__(256, 3) void p_mid(const unsigned short* __restrict__ Yin,
                        const unsigned short* __restrict__ pW, const float* __restrict__ bias,
                        unsigned short* __restrict__ Yout, float* __restrict__ stats,
                        int offSum, int offSq, float* __restrict__ sink) {
  __shared__ unsigned short As[64 * ASM];
  __shared__ float ssum[256], ssq[256];
  const int tid = threadIdx.x;
  const int lane = tid & 63, wave = tid >> 6;
  const int wc = wave % 4, wr = wave / 4;
  const int wrow = wr * 64;
  const int wcolf = wc * 4;
  const int arow = lane & 15;
  const int koff = (lane >> 4) << 3;
  const int grp = lane >> 4;
  float guard = 0.f;

#pragma unroll 1
  for (int rep = 0; rep < 2; rep++) {
    const int bid = blockIdx.x * 2 + rep;
    const int brow = bid * 64;
    if (tid < 256) { ssum[tid] = 0.f; ssq[tid] = 0.f; }
    // staging (identical to real)
    for (int i = tid; i < 64 * 32; i += 256) {
      int row = i >> 5, c16 = i & 31;
      short8 v = *(const short8*)&Yin[((size_t)(brow + row)) * 256 + c16 * 8];
      *(short8*)&As[row * ASM + c16 * 8] = v;
      if (MODE == 2) guard += bf2f((unsigned short)v[0]);  // keep loads live when K-loop absent
    }
    __syncthreads();

    f32x4 zero4 = {0.f, 0.f, 0.f, 0.f};
    f32x4 acc[4][4];
#pragma unroll
    for (int mf = 0; mf < 4; mf++)
#pragma unroll
      for (int nf = 0; nf < 4; nf++) acc[mf][nf] = zero4;

    if (MODE != 2) {
      short8 bcur[4], bnxt[4];
#pragma unroll
      for (int nf = 0; nf < 4; nf++)
        bcur[nf] = *(const short8*)&pW[(size_t)((wcolf + nf) * 64 + lane) * 8];
#pragma unroll
      for (int ks = 0; ks < 8; ks++) {
        if (ks + 1 < 8) {
#pragma unroll
          for (int nf = 0; nf < 4; nf++)
            bnxt[nf] = *(const short8*)&pW[(size_t)(((ks + 1) * 16 + wcolf + nf) * 64 + lane) * 8];
        }
#pragma unroll
        for (int mf = 0; mf < 4; mf++) {
          short8 am = *(const short8*)&As[(wrow + mf * 16 + arow) * ASM + ks * 32 + koff];
#pragma unroll
          for (int nf = 0; nf < 4; nf++)
            acc[mf][nf] = __builtin_amdgcn_mfma_f32_16x16x32_bf16(bcur[nf], am, acc[mf][nf], 0, 0, 0);
        }
#pragma unroll
        for (int nf = 0; nf < 4; nf++) bcur[nf] = bnxt[nf];
      }
    }
    __syncthreads();

    if (MODE == 1) {
      // keep acc (and thus MFMA + B loads + As reads) live; skip epilogue
#pragma unroll
      for (int mf = 0; mf < 4; mf++)
#pragma unroll
        for (int nf = 0; nf < 4; nf++)
#pragma unroll
          for (int j = 0; j < 4; j++) guard += acc[mf][nf][j];
    } else {
      // epilogue (identical to real)
      float* gsum = stats + (size_t)(bid & (NCOPY - 1)) * 1280 + offSum;
      float* gsq  = stats + (size_t)(bid & (NCOPY - 1)) * 1280 + offSq;
#pragma unroll
      for (int nf = 0; nf < 4; nf++) {
        const int c0 = (wcolf + nf) * 16 + grp * 4;
        f32x4 bb = *(const f32x4*)&bias[c0];
        float s[4] = {0.f, 0.f, 0.f, 0.f}, q[4] = {0.f, 0.f, 0.f, 0.f};
#pragma unroll
        for (int mf = 0; mf < 4; mf++) {
          const int r = wrow + mf * 16 + arow;
          unsigned short o[4];
#pragma unroll
          for (int j = 0; j < 4; j++) {
            float v = fmaxf(acc[mf][nf][j] + bb[j], 0.f);
            o[j] = f2bf(v);
            s[j] += v;
            q[j] += v * v;
          }
          *(ushort4w*)&As[r * ASM + c0] = *(ushort4w*)o;
        }
#pragma unroll
        for (int d = 1; d < 16; d <<= 1) {
#pragma unroll
          for (int j = 0; j < 4; j++) {
            s[j] += __shfl_xor(s[j], d, 64);
            q[j] += __shfl_xor(q[j], d, 64);
          }
        }
        if ((lane & 15) == 0) {
#pragma unroll
          for (int j = 0; j < 4; j++) {
            atomicAdd(&ssum[c0 + j], s[j]);
            atomicAdd(&ssq[c0 + j], q[j]);
          }
        }
      }
      __syncthreads();
      for (int i = tid; i < 64 * 32; i += 256) {
        int row = i >> 5, ch = i & 31;
        *(short8*)&Yout[(size_t)(brow + row) * 256 + ch * 8] = *(const short8*)&As[row * ASM + ch * 8];
      }
      if (tid < 256) {
        atomicAdd(&gsum[tid], ssum[tid]);
        atomicAdd(&gsq[tid], ssq[tid]);
      }
    }
    __syncthreads();
  }
  if (guard == 123456789.0f) sink[tid] = guard;  // never true; defeats DCE
}

extern "C" void kernel_launch(void* const* d_in, const int* in_sizes, int n_in,
                              void* d_out, int out_size, void* d_ws, size_t ws_size,
                              hipStream_t stream) {
  const int* x = (const int*)d_in[0];
  const float* tables = (const float*)d_in[1];
  const float* W0 = (const float*)d_in[2];
  const float* b0 = (const float*)d_in[3];
  const float* g0 = (const float*)d_in[4];
  const float* be0 = (const float*)d_in[5];
  const float* W1 = (const float*)d_in[6];
  const float* b1 = (const float*)d_in[7];
  const float* g1 = (const float*)d_in[8];
  const float* be1 = (const float*)d_in[9];
  const float* W2 = (const float*)d_in[10];
  const float* b2 = (const float*)d_in[11];
  const float* g2 = (const float*)d_in[12];
  const float* be2 = (const float*)d_in[13];
  const float* Wout = (const float*)d_in[14];
  const float* bout = (const float*)d_in[15];
  float* out = (float*)d_out;

  char* ws = (char*)d_ws;
  unsigned short* Y = (unsigned short*)ws;
  size_t off = (size_t)BR * 256 * 2;  // 134,217,728
  unsigned short* pW0 = (unsigned short*)(ws + off); off += (size_t)9 * 16 * 64 * 8 * 2;
  unsigned short* pW1 = (unsigned short*)(ws + off); off += (size_t)8 * 16 * 64 * 8 * 2;
  unsigned short* pW2 = (unsigned short*)(ws + off); off += (size_t)8 * 8 * 64 * 8 * 2;
  float* b1p = (float*)(ws + off); off += 1024;
  float* b2p = (float*)(ws + off); off += 512;
  float* woutp = (float*)(ws + off); off += 512;
  float* boutp = (float*)(ws + off); off += 256;
  float* stats = (float*)(ws + off); off += (size_t)NCOPY * 1280 * 4;
  unsigned short* tb = (unsigned short*)(ws + off); off += (size_t)17 * MAXR * 16 * 2;

  const int oS0 = 0, oQ0 = 256, oS1 = 512, oQ1 = 768, oS2 = 1024, oQ2 = 1152;

  k_prep0<<<64, 256, 0, stream>>>(W0, tables, pW0, tb, stats);
  k_gemm0<<<BR / 64, 256, 0, stream>>>(x, tb, pW0, b0, Y, stats, oS0, oQ0);
  k_fold<256, 256><<<16, 256, 0, stream>>>(stats, oS0, oQ0, g0, be0, W1, b1, pW1, b1p);
  k_gemm_mid<256, 4><<<BR / 64, 256, 0, stream>>>(Y, pW1, b1p, Y, stats, oS1, oQ1);
  k_fold<256, 128><<<16, 256, 0, stream>>>(stats, oS1, oQ1, g1, be1, W2, b2, pW2, b2p);
  k_gemm_mid<128, 2><<<BR / 64, 256, 0, stream>>>(Y, pW2, b2p, Y, stats, oS2, oQ2);
  k_foldout<<<1, 128, 0, stream>>>(stats, oS2, oQ2, g2, be2, Wout, bout, woutp, boutp);
  k_out<<<BR / 32, 256, 0, stream>>>(Y, woutp, boutp, out);
  // diagnostic ablation probes (Y/stats are dead here; d_out untouched)
  p_mid<0><<<BR / 128, 256, 0, stream>>>(Y, pW1, b1p, Y, stats, oS1, oQ1, stats);
  p_mid<1><<<BR / 128, 256, 0, stream>>>(Y, pW1, b1p, Y, stats, oS1, oQ1, stats);
  p_mid<2><<<BR / 128, 256, 0, stream>>>(Y, pW1, b1p, Y, stats, oS1, oQ1, stats);
}

// Round 10
// 380.504 us; speedup vs baseline: 1.6116x; 1.6116x over previous
//
#include <hip/hip_runtime.h>
#include <stdint.h>

#define BR 262144
#define NTAB 17
#define MAXR 512
#define DIN 272
#define AS0 296   // LDS row stride (bf16) layer0 (K padded to 288); also C-restage stride
#define NCOPY 32
#define BNEPS 1e-5f
#define TPB 4     // tiles per mid-layer block (pipelined)

typedef __attribute__((ext_vector_type(8))) short short8;
typedef __attribute__((ext_vector_type(4))) float f32x4;
typedef __attribute__((ext_vector_type(4))) unsigned short ushort4w;
typedef unsigned int u32;

__device__ __forceinline__ unsigned short f2bf(float f) {
  union { float f; unsigned u; } v; v.f = f;
  return (unsigned short)((v.u + 0x7FFFu + ((v.u >> 16) & 1u)) >> 16);
}
__device__ __forceinline__ float bf2f(unsigned short h) {
  union { unsigned u; float f; } v; v.u = ((unsigned)h) << 16;
  return v.f;
}
// async global->LDS: 16B/lane, LDS dest = wave-uniform base + lane*16
__device__ __forceinline__ void gload_lds16(const void* g, void* l) {
  __builtin_amdgcn_global_load_lds((const __attribute__((address_space(1))) u32*)g,
                                   (__attribute__((address_space(3))) u32*)l, 16, 0, 0);
}

// ---------- prep: tables f32 -> bf16; pack W0 -> MFMA B-frags; zero stats ----------
__global__ void k_prep0(const float* __restrict__ W0, const float* __restrict__ tables,
                        unsigned short* __restrict__ pW0, unsigned short* __restrict__ tb,
                        float* __restrict__ stats) {
  int tid = blockIdx.x * blockDim.x + threadIdx.x;
  int nth = gridDim.x * blockDim.x;
  for (int i = tid; i < NCOPY * 1280; i += nth) stats[i] = 0.f;
  for (int e = tid; e < 17408; e += nth) {
    const float* src = tables + (size_t)e * 8;
    f32x4 v0 = ((const f32x4*)src)[0];
    f32x4 v1 = ((const f32x4*)src)[1];
    unsigned short tmp[8];
#pragma unroll
    for (int j = 0; j < 4; j++) { tmp[j] = f2bf(v0[j]); tmp[4 + j] = f2bf(v1[j]); }
    *(short8*)&tb[(size_t)e * 8] = *(short8*)tmp;
  }
  for (int e = tid; e < 9 * 16 * 64; e += nth) {
    int l = e & 63, f = e >> 6;
    int nf = f & 15, ks = f >> 4;
    int col = nf * 16 + (l & 15);
    int kb = ks * 32 + ((l >> 4) << 3);
    unsigned short tmp[8];
#pragma unroll
    for (int j = 0; j < 8; j++) {
      int k = kb + j;
      tmp[j] = f2bf(k < DIN ? W0[k * 256 + col] : 0.f);
    }
    *(short8*)&pW0[(size_t)e * 8] = *(short8*)tmp;
  }
}

// ---------- fold BN(layer l) into W(l+1) ----------
template <int KP, int NP>
__global__ void k_fold(const float* __restrict__ stats, int offSum, int offSq,
                       const float* __restrict__ g, const float* __restrict__ be,
                       const float* __restrict__ W, const float* __restrict__ b,
                       unsigned short* __restrict__ pW, float* __restrict__ bOut) {
  __shared__ float sa[KP], sc[KP];
  int tid = threadIdx.x;  // 256
  if (tid < KP) {
    float s = 0.f, q = 0.f;
    for (int c = 0; c < NCOPY; c++) {
      s += stats[c * 1280 + offSum + tid];
      q += stats[c * 1280 + offSq + tid];
    }
    float mu = s * (1.f / BR);
    float var = fmaxf(q * (1.f / BR) - mu * mu, 0.f);
    float a = g[tid] * rsqrtf(var + BNEPS);
    sa[tid] = a;
    sc[tid] = be[tid] - mu * a;
  }
  __syncthreads();
  const int NFT = NP / 16;
  const int ENT = (KP / 32) * NFT * 64;
  for (int e = blockIdx.x * blockDim.x + tid; e < ENT; e += gridDim.x * blockDim.x) {
    int l = e & 63, f = e >> 6;
    int nf = f % NFT, ks = f / NFT;
    int col = nf * 16 + (l & 15);
    int kb = ks * 32 + ((l >> 4) << 3);
    unsigned short tmp[8];
#pragma unroll
    for (int j = 0; j < 8; j++) {
      int k = kb + j;
      tmp[j] = f2bf(sa[k] * W[k * NP + col]);
    }
    *(short8*)&pW[(size_t)e * 8] = *(short8*)tmp;
  }
  if (blockIdx.x == 0 && tid < NP) {
    float s = b[tid];
    for (int k = 0; k < KP; k++) s += sc[k] * W[k * NP + tid];
    bOut[tid] = s;
  }
}

// ---------- fold BN(layer2) into Wout ----------
__global__ void k_foldout(const float* __restrict__ stats, int offSum, int offSq,
                          const float* __restrict__ g, const float* __restrict__ be,
                          const float* __restrict__ Wout, const float* __restrict__ bout,
                          float* __restrict__ woutp, float* __restrict__ boutp) {
  __shared__ float red[128];
  int tid = threadIdx.x;  // 128 threads
  float s = 0.f, q = 0.f;
  for (int c = 0; c < NCOPY; c++) {
    s += stats[c * 1280 + offSum + tid];
    q += stats[c * 1280 + offSq + tid];
  }
  float mu = s * (1.f / BR);
  float var = fmaxf(q * (1.f / BR) - mu * mu, 0.f);
  float a = g[tid] * rsqrtf(var + BNEPS);
  float c = be[tid] - mu * a;
  float w = Wout[tid];
  woutp[tid] = a * w;
  red[tid] = c * w;
  __syncthreads();
  for (int st = 64; st > 0; st >>= 1) {
    if (tid < st) red[tid] += red[tid + st];
    __syncthreads();
  }
  if (tid == 0) boutp[0] = red[0] + bout[0];
}

// ---------- shared GEMM body (R4-verified; used by gemm0 only) ----------
template <int KSTEPS, int N, int AST, int MF>
__device__ __forceinline__ void gemm_body(unsigned short* As, const unsigned short* __restrict__ pW,
                                          const float* __restrict__ bias, unsigned short* __restrict__ Y,
                                          int brow, float* ssum, float* ssq,
                                          float* __restrict__ gsum, float* __restrict__ gsq) {
  const int tid = threadIdx.x;
  const int lane = tid & 63, wave = tid >> 6;
  constexpr int WC = N / 64;
  const int wc = wave % WC, wr = wave / WC;
  const int wrow = wr * (MF * 16);
  const int wcolf = wc * 4;
  const int arow = lane & 15;
  const int koff = (lane >> 4) << 3;
  const int grp = lane >> 4;

  f32x4 zero4 = {0.f, 0.f, 0.f, 0.f};
  f32x4 acc[MF][4];
#pragma unroll
  for (int mf = 0; mf < MF; mf++)
#pragma unroll
    for (int nf = 0; nf < 4; nf++) acc[mf][nf] = zero4;

  short8 bcur[4], bnxt[4];
#pragma unroll
  for (int nf = 0; nf < 4; nf++)
    bcur[nf] = *(const short8*)&pW[(size_t)((wcolf + nf) * 64 + lane) * 8];

#pragma unroll
  for (int ks = 0; ks < KSTEPS; ks++) {
    if (ks + 1 < KSTEPS) {
#pragma unroll
      for (int nf = 0; nf < 4; nf++)
        bnxt[nf] = *(const short8*)&pW[(size_t)(((ks + 1) * (N / 16) + wcolf + nf) * 64 + lane) * 8];
    }
#pragma unroll
    for (int mf = 0; mf < MF; mf++) {
      short8 am = *(const short8*)&As[(wrow + mf * 16 + arow) * AST + ks * 32 + koff];
#pragma unroll
      for (int nf = 0; nf < 4; nf++)
        acc[mf][nf] = __builtin_amdgcn_mfma_f32_16x16x32_bf16(bcur[nf], am, acc[mf][nf], 0, 0, 0);
    }
#pragma unroll
    for (int nf = 0; nf < 4; nf++) bcur[nf] = bnxt[nf];
  }

  __syncthreads();

#pragma unroll
  for (int nf = 0; nf < 4; nf++) {
    const int c0 = (wcolf + nf) * 16 + grp * 4;
    f32x4 bb = *(const f32x4*)&bias[c0];
    float s[4] = {0.f, 0.f, 0.f, 0.f}, q[4] = {0.f, 0.f, 0.f, 0.f};
#pragma unroll
    for (int mf = 0; mf < MF; mf++) {
      const int r = wrow + mf * 16 + arow;
      unsigned short o[4];
#pragma unroll
      for (int j = 0; j < 4; j++) {
        float v = fmaxf(acc[mf][nf][j] + bb[j], 0.f);
        o[j] = f2bf(v);
        s[j] += v;
        q[j] += v * v;
      }
      *(ushort4w*)&As[r * AST + c0] = *(ushort4w*)o;
    }
#pragma unroll
    for (int d = 1; d < 16; d <<= 1) {
#pragma unroll
      for (int j = 0; j < 4; j++) {
        s[j] += __shfl_xor(s[j], d, 64);
        q[j] += __shfl_xor(q[j], d, 64);
      }
    }
    if ((lane & 15) == 0) {
#pragma unroll
      for (int j = 0; j < 4; j++) {
        atomicAdd(&ssum[c0 + j], s[j]);
        atomicAdd(&ssq[c0 + j], q[j]);
      }
    }
  }
  __syncthreads();

  constexpr int CH = N / 8;
  for (int i = tid; i < 64 * CH; i += 256) {
    int row = i / CH, ch = i % CH;
    *(short8*)&Y[(size_t)(brow + row) * 256 + ch * 8] = *(const short8*)&As[row * AST + ch * 8];
  }
  if (tid < N) {
    atomicAdd(&gsum[tid], ssum[tid]);
    atomicAdd(&gsq[tid], ssq[tid]);
  }
}

// ---------- layer 0: embedding gather (bf16 tables, LDS-staged indices) + GEMM (R4 exact) ----------
__global__ __launch_bounds__(256, 3) void k_gemm0(const int* __restrict__ x, const unsigned short* __restrict__ tb,
                        const unsigned short* __restrict__ pW, const float* __restrict__ bias,
                        unsigned short* __restrict__ Y, float* __restrict__ stats, int offSum, int offSq) {
  __shared__ unsigned short As[64 * AS0];
  __shared__ int sx[64 * NTAB];
  __shared__ float ssum[256], ssq[256];
  const int tid = threadIdx.x;
  if (tid < 256) { ssum[tid] = 0.f; ssq[tid] = 0.f; }
  const int brow = blockIdx.x * 64;
  for (int t = tid; t < 64 * NTAB; t += 256) sx[t] = x[brow * NTAB + t];
  short8 z8 = {0, 0, 0, 0, 0, 0, 0, 0};
  for (int t = tid; t < 64; t += 256) {
    *(short8*)&As[t * AS0 + 272] = z8;
    *(short8*)&As[t * AS0 + 280] = z8;
    *(short8*)&As[t * AS0 + 288] = z8;
  }
  __syncthreads();
  for (int i = tid; i < 64 * NTAB * 2; i += 256) {
    int r = i / (NTAB * 2);
    int rem = i - r * (NTAB * 2);
    int tbl = rem >> 1, half = rem & 1;
    int idx = sx[r * NTAB + tbl];
    short8 v = *(const short8*)&tb[((size_t)(tbl * MAXR + idx)) * 16 + half * 8];
    *(short8*)&As[r * AS0 + tbl * 16 + half * 8] = v;
  }
  __syncthreads();
  float* gsum = stats + (size_t)(blockIdx.x & (NCOPY - 1)) * 1280 + offSum;
  float* gsq  = stats + (size_t)(blockIdx.x & (NCOPY - 1)) * 1280 + offSq;
  gemm_body<9, 256, AS0, 4>(As, pW, bias, Y, brow, ssum, ssq, gsum, gsq);
}

// ---------- mid layers: TPB-tile pipeline, gload_lds double-buffer, XOR-swizzled LDS ----------
// LDS tile [64][256] (unpadded, linear for gload_lds). Swizzle: 16B-chunk c stored at c^(row&7).
// Stage source addresses pre-apply the XOR (rule 21 both-sides). Y stays row-major.
template <int N, int MF>
__global__ __launch_bounds__(256, 2) void k_gemm_mid(const unsigned short* __restrict__ Yin,
                           const unsigned short* __restrict__ pW, const float* __restrict__ bias,
                           unsigned short* __restrict__ Y, float* __restrict__ stats, int offSum, int offSq) {
  __shared__ unsigned short As[2][64 * 256];
  const int tid = threadIdx.x;
  const int lane = tid & 63, wave = tid >> 6;
  constexpr int WC = N / 64;
  const int wc = wave % WC, wr = wave / WC;
  const int wrow = wr * (MF * 16);
  const int wcolf = wc * 4;
  const int arow = lane & 15;
  const int grp = lane >> 4;
  const int tbeg = blockIdx.x * TPB;

  // stage-address precompute (per thread, fixed across tiles)
  const int sr[8] = {wave * 16 + 0 + (lane >> 5), wave * 16 + 2 + (lane >> 5),
                     wave * 16 + 4 + (lane >> 5), wave * 16 + 6 + (lane >> 5),
                     wave * 16 + 8 + (lane >> 5), wave * 16 + 10 + (lane >> 5),
                     wave * 16 + 12 + (lane >> 5), wave * 16 + 14 + (lane >> 5)};

  // prologue: stage tile tbeg into buf 0
#pragma unroll
  for (int k = 0; k < 8; k++) {
    int r = sr[k];
    int c = (lane & 31) ^ (r & 7);
    gload_lds16(&Yin[(size_t)(tbeg * 64 + r) * 256 + c * 8], &As[0][(wave * 8 + k) * 512]);
  }
  asm volatile("s_waitcnt vmcnt(0)" ::: "memory");
  __builtin_amdgcn_s_barrier();
  __builtin_amdgcn_sched_barrier(0);

#pragma unroll 1
  for (int ti = 0; ti < TPB; ti++) {
    const int tile = tbeg + ti;
    const int buf = ti & 1;
    const unsigned short* A = &As[buf][0];

    // K-loop: B depth-1 prefetch from L2; A from swizzled LDS
    f32x4 zero4 = {0.f, 0.f, 0.f, 0.f};
    f32x4 acc[MF][4];
#pragma unroll
    for (int mf = 0; mf < MF; mf++)
#pragma unroll
      for (int nf = 0; nf < 4; nf++) acc[mf][nf] = zero4;

    short8 bcur[4], bnxt[4];
#pragma unroll
    for (int nf = 0; nf < 4; nf++)
      bcur[nf] = *(const short8*)&pW[(size_t)((wcolf + nf) * 64 + lane) * 8];
#pragma unroll
    for (int ks = 0; ks < 8; ks++) {
      if (ks + 1 < 8) {
#pragma unroll
        for (int nf = 0; nf < 4; nf++)
          bnxt[nf] = *(const short8*)&pW[(size_t)(((ks + 1) * (N / 16) + wcolf + nf) * 64 + lane) * 8];
      }
#pragma unroll
      for (int mf = 0; mf < MF; mf++) {
        const int ar = wrow + mf * 16 + arow;
        short8 am = *(const short8*)&A[ar * 256 + (((ks * 4 + grp) ^ (ar & 7)) << 3)];
#pragma unroll
        for (int nf = 0; nf < 4; nf++)
          acc[mf][nf] = __builtin_amdgcn_mfma_f32_16x16x32_bf16(bcur[nf], am, acc[mf][nf], 0, 0, 0);
      }
#pragma unroll
      for (int nf = 0; nf < 4; nf++) bcur[nf] = bnxt[nf];
    }

    // issue next tile's stage AFTER all K-loop B-loads (in-order vmcnt: keep stage youngest)
    if (ti + 1 < TPB) {
#pragma unroll
      for (int k = 0; k < 8; k++) {
        int r = sr[k];
        int c = (lane & 31) ^ (r & 7);
        gload_lds16(&Yin[(size_t)((tile + 1) * 64 + r) * 256 + c * 8], &As[buf ^ 1][(wave * 8 + k) * 512]);
      }
    }
    asm volatile("" ::: "memory");
    __builtin_amdgcn_s_barrier();   // all waves done READING As[buf] (K-loop data already consumed)
    __builtin_amdgcn_sched_barrier(0);

    // epilogue: bias+relu -> restage into As[buf] (swizzled) + direct global stats atomics
    float* gsum = stats + (size_t)(tile & (NCOPY - 1)) * 1280 + offSum;
    float* gsq  = stats + (size_t)(tile & (NCOPY - 1)) * 1280 + offSq;
#pragma unroll
    for (int nf = 0; nf < 4; nf++) {
      const int c0 = (wcolf + nf) * 16 + grp * 4;
      const int cch = (wcolf + nf) * 2 + (grp >> 1);  // 16B chunk index
      f32x4 bb = *(const f32x4*)&bias[c0];
      float s[4] = {0.f, 0.f, 0.f, 0.f}, q[4] = {0.f, 0.f, 0.f, 0.f};
#pragma unroll
      for (int mf = 0; mf < MF; mf++) {
        const int r = wrow + mf * 16 + arow;
        unsigned short o[4];
#pragma unroll
        for (int j = 0; j < 4; j++) {
          float v = fmaxf(acc[mf][nf][j] + bb[j], 0.f);
          o[j] = f2bf(v);
          s[j] += v;
          q[j] += v * v;
        }
        *(ushort4w*)&As[buf][r * 256 + ((cch ^ (r & 7)) << 3) + (grp & 1) * 4] = *(ushort4w*)o;
      }
#pragma unroll
      for (int d = 1; d < 16; d <<= 1) {
#pragma unroll
        for (int j = 0; j < 4; j++) {
          s[j] += __shfl_xor(s[j], d, 64);
          q[j] += __shfl_xor(q[j], d, 64);
        }
      }
      if ((lane & 15) == 0) {
#pragma unroll
        for (int j = 0; j < 4; j++) {
          atomicAdd(&gsum[c0 + j], s[j]);
          atomicAdd(&gsq[c0 + j], q[j]);
        }
      }
    }
    asm volatile("s_waitcnt lgkmcnt(0)" ::: "memory");
    __builtin_amdgcn_s_barrier();   // restage writes visible
    __builtin_amdgcn_sched_barrier(0);

    // coalesced row-major Y store (16B/lane) from swizzled LDS
    constexpr int CH = N / 8;
    for (int i = tid; i < 64 * CH; i += 256) {
      int row = i / CH, c = i % CH;
      short8 v = *(const short8*)&As[buf][row * 256 + ((c ^ (row & 7)) << 3)];
      *(short8*)&Y[(size_t)(tile * 64 + row) * 256 + c * 8] = v;
    }
    asm volatile("s_waitcnt vmcnt(0)" ::: "memory");  // next tile's stage landed (+stores drained)
    __builtin_amdgcn_s_barrier();
    __builtin_amdgcn_sched_barrier(0);
  }
}

// ---------- final dot (R4 exact) ----------
__global__ void k_out(const unsigned short* __restrict__ Y, const float* __restrict__ woutp,
                      const float* __restrict__ boutp, float* __restrict__ out) {
  __shared__ float w[128];
  const int tid = threadIdx.x;
  if (tid < 128) w[tid] = woutp[tid];
  __syncthreads();
  const int lane = tid & 63, wave = tid >> 6;
  const int sub = lane & 7, rloc = lane >> 3;
  const int row = blockIdx.x * 32 + wave * 8 + rloc;
  const unsigned short* yr = &Y[(size_t)row * 256 + sub * 16];
  short8 v0 = *(const short8*)yr;
  short8 v1 = *(const short8*)(yr + 8);
  float acc = 0.f;
#pragma unroll
  for (int j = 0; j < 8; j++) acc += bf2f((unsigned short)v0[j]) * w[sub * 16 + j];
#pragma unroll
  for (int j = 0; j < 8; j++) acc += bf2f((unsigned short)v1[j]) * w[sub * 16 + 8 + j];
  acc += __shfl_xor(acc, 1, 64);
  acc += __shfl_xor(acc, 2, 64);
  acc += __shfl_xor(acc, 4, 64);
  if (sub == 0) out[row] = acc + boutp[0];
}

extern "C" void kernel_launch(void* const* d_in, const int* in_sizes, int n_in,
                              void* d_out, int out_size, void* d_ws, size_t ws_size,
                              hipStream_t stream) {
  const int* x = (const int*)d_in[0];
  const float* tables = (const float*)d_in[1];
  const float* W0 = (const float*)d_in[2];
  const float* b0 = (const float*)d_in[3];
  const float* g0 = (const float*)d_in[4];
  const float* be0 = (const float*)d_in[5];
  const float* W1 = (const float*)d_in[6];
  const float* b1 = (const float*)d_in[7];
  const float* g1 = (const float*)d_in[8];
  const float* be1 = (const float*)d_in[9];
  const float* W2 = (const float*)d_in[10];
  const float* b2 = (const float*)d_in[11];
  const float* g2 = (const float*)d_in[12];
  const float* be2 = (const float*)d_in[13];
  const float* Wout = (const float*)d_in[14];
  const float* bout = (const float*)d_in[15];
  float* out = (float*)d_out;

  char* ws = (char*)d_ws;
  unsigned short* Y = (unsigned short*)ws;
  size_t off = (size_t)BR * 256 * 2;  // 134,217,728
  unsigned short* pW0 = (unsigned short*)(ws + off); off += (size_t)9 * 16 * 64 * 8 * 2;
  unsigned short* pW1 = (unsigned short*)(ws + off); off += (size_t)8 * 16 * 64 * 8 * 2;
  unsigned short* pW2 = (unsigned short*)(ws + off); off += (size_t)8 * 8 * 64 * 8 * 2;
  float* b1p = (float*)(ws + off); off += 1024;
  float* b2p = (float*)(ws + off); off += 512;
  float* woutp = (float*)(ws + off); off += 512;
  float* boutp = (float*)(ws + off); off += 256;
  float* stats = (float*)(ws + off); off += (size_t)NCOPY * 1280 * 4;
  unsigned short* tb = (unsigned short*)(ws + off); off += (size_t)17 * MAXR * 16 * 2;

  const int oS0 = 0, oQ0 = 256, oS1 = 512, oQ1 = 768, oS2 = 1024, oQ2 = 1152;

  k_prep0<<<64, 256, 0, stream>>>(W0, tables, pW0, tb, stats);
  k_gemm0<<<BR / 64, 256, 0, stream>>>(x, tb, pW0, b0, Y, stats, oS0, oQ0);
  k_fold<256, 256><<<16, 256, 0, stream>>>(stats, oS0, oQ0, g0, be0, W1, b1, pW1, b1p);
  k_gemm_mid<256, 4><<<BR / 64 / TPB, 256, 0, stream>>>(Y, pW1, b1p, Y, stats, oS1, oQ1);
  k_fold<256, 128><<<16, 256, 0, stream>>>(stats, oS1, oQ1, g1, be1, W2, b2, pW2, b2p);
  k_gemm_mid<128, 2><<<BR / 64 / TPB, 256, 0, stream>>>(Y, pW2, b2p, Y, stats, oS2, oQ2);
  k_foldout<<<1, 128, 0, stream>>>(stats, oS2, oQ2, g2, be2, Wout, bout, woutp, boutp);
  k_out<<<BR / 32, 256, 0, stream>>>(Y, woutp, boutp, out);
}

// Round 11
// 221.029 us; speedup vs baseline: 2.7744x; 1.7215x over previous
//
#include <hip/hip_runtime.h>
#include <stdint.h>

#define BR 262144
#define NTAB 17
#define MAXR 512
#define DIN 272
#define AS0 296   // LDS row stride (bf16) layer0 (K padded to 288); also C-restage stride
#define ASM 264   // LDS row stride (bf16) mid layers (K=256); also C-restage stride
#define NCOPY 32
#define BNEPS 1e-5f

typedef __attribute__((ext_vector_type(8))) short short8;
typedef __attribute__((ext_vector_type(4))) float f32x4;
typedef __attribute__((ext_vector_type(4))) unsigned short ushort4w;

__device__ __forceinline__ unsigned short f2bf(float f) {
  union { float f; unsigned u; } v; v.f = f;
  return (unsigned short)((v.u + 0x7FFFu + ((v.u >> 16) & 1u)) >> 16);
}
__device__ __forceinline__ float bf2f(unsigned short h) {
  union { unsigned u; float f; } v; v.u = ((unsigned)h) << 16;
  return v.f;
}

// ---------- prep: tables f32 -> bf16; pack W0 -> MFMA B-frags; zero stats ----------
__global__ void k_prep0(const float* __restrict__ W0, const float* __restrict__ tables,
                        unsigned short* __restrict__ pW0, unsigned short* __restrict__ tb,
                        float* __restrict__ stats) {
  int tid = blockIdx.x * blockDim.x + threadIdx.x;
  int nth = gridDim.x * blockDim.x;
  for (int i = tid; i < NCOPY * 1280; i += nth) stats[i] = 0.f;
  for (int e = tid; e < 17408; e += nth) {
    const float* src = tables + (size_t)e * 8;
    f32x4 v0 = ((const f32x4*)src)[0];
    f32x4 v1 = ((const f32x4*)src)[1];
    unsigned short tmp[8];
#pragma unroll
    for (int j = 0; j < 4; j++) { tmp[j] = f2bf(v0[j]); tmp[4 + j] = f2bf(v1[j]); }
    *(short8*)&tb[(size_t)e * 8] = *(short8*)tmp;
  }
  for (int e = tid; e < 9 * 16 * 64; e += nth) {
    int l = e & 63, f = e >> 6;
    int nf = f & 15, ks = f >> 4;
    int col = nf * 16 + (l & 15);
    int kb = ks * 32 + ((l >> 4) << 3);
    unsigned short tmp[8];
#pragma unroll
    for (int j = 0; j < 8; j++) {
      int k = kb + j;
      tmp[j] = f2bf(k < DIN ? W0[k * 256 + col] : 0.f);
    }
    *(short8*)&pW0[(size_t)e * 8] = *(short8*)tmp;
  }
}

// ---------- fold BN(layer l) into W(l+1) ----------
template <int KP, int NP>
__global__ void k_fold(const float* __restrict__ stats, int offSum, int offSq,
                       const float* __restrict__ g, const float* __restrict__ be,
                       const float* __restrict__ W, const float* __restrict__ b,
                       unsigned short* __restrict__ pW, float* __restrict__ bOut) {
  __shared__ float sa[KP], sc[KP];
  int tid = threadIdx.x;  // 256
  if (tid < KP) {
    float s = 0.f, q = 0.f;
    for (int c = 0; c < NCOPY; c++) {
      s += stats[c * 1280 + offSum + tid];
      q += stats[c * 1280 + offSq + tid];
    }
    float mu = s * (1.f / BR);
    float var = fmaxf(q * (1.f / BR) - mu * mu, 0.f);
    float a = g[tid] * rsqrtf(var + BNEPS);
    sa[tid] = a;
    sc[tid] = be[tid] - mu * a;
  }
  __syncthreads();
  const int NFT = NP / 16;
  const int ENT = (KP / 32) * NFT * 64;
  for (int e = blockIdx.x * blockDim.x + tid; e < ENT; e += gridDim.x * blockDim.x) {
    int l = e & 63, f = e >> 6;
    int nf = f % NFT, ks = f / NFT;
    int col = nf * 16 + (l & 15);
    int kb = ks * 32 + ((l >> 4) << 3);
    unsigned short tmp[8];
#pragma unroll
    for (int j = 0; j < 8; j++) {
      int k = kb + j;
      tmp[j] = f2bf(sa[k] * W[k * NP + col]);
    }
    *(short8*)&pW[(size_t)e * 8] = *(short8*)tmp;
  }
  if (blockIdx.x == 0 && tid < NP) {
    float s = b[tid];
    for (int k = 0; k < KP; k++) s += sc[k] * W[k * NP + tid];
    bOut[tid] = s;
  }
}

// ---------- fold BN(layer2) into Wout ----------
__global__ void k_foldout(const float* __restrict__ stats, int offSum, int offSq,
                          const float* __restrict__ g, const float* __restrict__ be,
                          const float* __restrict__ Wout, const float* __restrict__ bout,
                          float* __restrict__ woutp, float* __restrict__ boutp) {
  __shared__ float red[128];
  int tid = threadIdx.x;  // 128 threads
  float s = 0.f, q = 0.f;
  for (int c = 0; c < NCOPY; c++) {
    s += stats[c * 1280 + offSum + tid];
    q += stats[c * 1280 + offSq + tid];
  }
  float mu = s * (1.f / BR);
  float var = fmaxf(q * (1.f / BR) - mu * mu, 0.f);
  float a = g[tid] * rsqrtf(var + BNEPS);
  float c = be[tid] - mu * a;
  float w = Wout[tid];
  woutp[tid] = a * w;
  red[tid] = c * w;
  __syncthreads();
  for (int st = 64; st > 0; st >>= 1) {
    if (tid < st) red[tid] += red[tid + st];
    __syncthreads();
  }
  if (tid == 0) boutp[0] = red[0] + bout[0];
}

// ---------- shared GEMM body (R4 structure; stats moved to store phase) ----------
// swapped-operand MFMA acc frag: row = lane&15, col = (lane>>4)*4 + j  (verified R1-R10)
// sbuf: float[4][CH][16] scratch for cross-wave stats reduce.
template <int KSTEPS, int N, int AST, int MF>
__device__ __forceinline__ void gemm_body(unsigned short* As, float* sbuf,
                                          const unsigned short* __restrict__ pW,
                                          const float* __restrict__ bias, unsigned short* __restrict__ Y,
                                          int brow, float* __restrict__ gsum, float* __restrict__ gsq) {
  const int tid = threadIdx.x;
  const int lane = tid & 63, wave = tid >> 6;
  constexpr int WC = N / 64;
  constexpr int CH = N / 8;
  const int wc = wave % WC, wr = wave / WC;
  const int wrow = wr * (MF * 16);
  const int wcolf = wc * 4;
  const int arow = lane & 15;
  const int koff = (lane >> 4) << 3;
  const int grp = lane >> 4;

  f32x4 zero4 = {0.f, 0.f, 0.f, 0.f};
  f32x4 acc[MF][4];
#pragma unroll
  for (int mf = 0; mf < MF; mf++)
#pragma unroll
    for (int nf = 0; nf < 4; nf++) acc[mf][nf] = zero4;

  short8 bcur[4], bnxt[4];
#pragma unroll
  for (int nf = 0; nf < 4; nf++)
    bcur[nf] = *(const short8*)&pW[(size_t)((wcolf + nf) * 64 + lane) * 8];

#pragma unroll
  for (int ks = 0; ks < KSTEPS; ks++) {
    if (ks + 1 < KSTEPS) {
#pragma unroll
      for (int nf = 0; nf < 4; nf++)
        bnxt[nf] = *(const short8*)&pW[(size_t)(((ks + 1) * (N / 16) + wcolf + nf) * 64 + lane) * 8];
    }
#pragma unroll
    for (int mf = 0; mf < MF; mf++) {
      short8 am = *(const short8*)&As[(wrow + mf * 16 + arow) * AST + ks * 32 + koff];
#pragma unroll
      for (int nf = 0; nf < 4; nf++)
        acc[mf][nf] = __builtin_amdgcn_mfma_f32_16x16x32_bf16(bcur[nf], am, acc[mf][nf], 0, 0, 0);
    }
#pragma unroll
    for (int nf = 0; nf < 4; nf++) bcur[nf] = bnxt[nf];
  }

  __syncthreads();  // all As reads done; reuse As as C restage buffer (stride AST)

  // epilogue: bias + relu + bf16 restage to LDS (no stats here)
#pragma unroll
  for (int nf = 0; nf < 4; nf++) {
    const int c0 = (wcolf + nf) * 16 + grp * 4;
    f32x4 bb = *(const f32x4*)&bias[c0];
#pragma unroll
    for (int mf = 0; mf < MF; mf++) {
      const int r = wrow + mf * 16 + arow;
      unsigned short o[4];
#pragma unroll
      for (int j = 0; j < 4; j++) o[j] = f2bf(fmaxf(acc[mf][nf][j] + bb[j], 0.f));
      *(ushort4w*)&As[r * AST + c0] = *(ushort4w*)o;
    }
  }
  __syncthreads();

  // store phase: coalesced row-major Y store (16B/lane) + per-thread column stats
  // (ch = tid % CH is loop-invariant -> each thread owns 8 fixed columns)
  float s8[8] = {0.f, 0.f, 0.f, 0.f, 0.f, 0.f, 0.f, 0.f};
  float q8[8] = {0.f, 0.f, 0.f, 0.f, 0.f, 0.f, 0.f, 0.f};
  const int ch = tid % CH;
#pragma unroll
  for (int k = 0; k < (64 * CH) / 256; k++) {
    int i = tid + k * 256;
    int row = i / CH;
    short8 v = *(const short8*)&As[row * AST + ch * 8];
    *(short8*)&Y[(size_t)(brow + row) * 256 + ch * 8] = v;
#pragma unroll
    for (int j = 0; j < 8; j++) {
      float f = bf2f((unsigned short)v[j]);
      s8[j] += f;
      q8[j] += f * f;
    }
  }
  // fold lanes sharing the same ch within the wave (lanes l, l+CH, ...)
#pragma unroll
  for (int d = CH; d < 64; d <<= 1) {
#pragma unroll
    for (int j = 0; j < 8; j++) {
      s8[j] += __shfl_xor(s8[j], d, 64);
      q8[j] += __shfl_xor(q8[j], d, 64);
    }
  }
  if (lane < CH) {
    float* dst = &sbuf[(wave * CH + lane) * 16];
#pragma unroll
    for (int j = 0; j < 8; j++) { dst[j] = s8[j]; dst[8 + j] = q8[j]; }
  }
  __syncthreads();
  for (int o = tid; o < CH * 16; o += 256) {
    int c = o >> 4, v = o & 15;
    float t = sbuf[(0 * CH + c) * 16 + v] + sbuf[(1 * CH + c) * 16 + v] +
              sbuf[(2 * CH + c) * 16 + v] + sbuf[(3 * CH + c) * 16 + v];
    int col = c * 8 + (v & 7);
    atomicAdd((v < 8 ? gsum : gsq) + col, t);
  }
}

// ---------- layer 0: embedding gather (bf16 tables, direct idx loads) + GEMM ----------
__global__ __launch_bounds__(256, 3) void k_gemm0(const int* __restrict__ x, const unsigned short* __restrict__ tb,
                        const unsigned short* __restrict__ pW, const float* __restrict__ bias,
                        unsigned short* __restrict__ Y, float* __restrict__ stats, int offSum, int offSq) {
  __shared__ unsigned short As[64 * AS0];
  __shared__ float sbuf[4 * 32 * 16];
  const int tid = threadIdx.x;
  const int brow = blockIdx.x * 64;
  short8 z8 = {0, 0, 0, 0, 0, 0, 0, 0};
  for (int t = tid; t < 64; t += 256) {
    *(short8*)&As[t * AS0 + 272] = z8;
    *(short8*)&As[t * AS0 + 280] = z8;
    *(short8*)&As[t * AS0 + 288] = z8;
  }
  for (int i = tid; i < 64 * NTAB * 2; i += 256) {
    int r = i / (NTAB * 2);
    int rem = i - r * (NTAB * 2);
    int tbl = rem >> 1, half = rem & 1;
    int idx = x[(brow + r) * NTAB + tbl];
    short8 v = *(const short8*)&tb[((size_t)(tbl * MAXR + idx)) * 16 + half * 8];
    *(short8*)&As[r * AS0 + tbl * 16 + half * 8] = v;
  }
  __syncthreads();
  float* gsum = stats + (size_t)(blockIdx.x & (NCOPY - 1)) * 1280 + offSum;
  float* gsq  = stats + (size_t)(blockIdx.x & (NCOPY - 1)) * 1280 + offSq;
  gemm_body<9, 256, AS0, 4>(As, sbuf, pW, bias, Y, brow, gsum, gsq);
}

// ---------- mid layers ----------
template <int N, int MF>
__global__ __launch_bounds__(256, 3) void k_gemm_mid(const unsigned short* __restrict__ Yin,
                           const unsigned short* __restrict__ pW, const float* __restrict__ bias,
                           unsigned short* __restrict__ Y, float* __restrict__ stats, int offSum, int offSq) {
  __shared__ unsigned short As[64 * ASM];
  __shared__ float sbuf[4 * (N / 8) * 16];
  const int tid = threadIdx.x;
  const int brow = blockIdx.x * 64;
  for (int i = tid; i < 64 * 32; i += 256) {
    int row = i >> 5, c16 = i & 31;
    short8 v = *(const short8*)&Yin[((size_t)(brow + row)) * 256 + c16 * 8];
    *(short8*)&As[row * ASM + c16 * 8] = v;
  }
  __syncthreads();
  float* gsum = stats + (size_t)(blockIdx.x & (NCOPY - 1)) * 1280 + offSum;
  float* gsq  = stats + (size_t)(blockIdx.x & (NCOPY - 1)) * 1280 + offSq;
  gemm_body<8, N, ASM, MF>(As, sbuf, pW, bias, Y, brow, gsum, gsq);
}

// ---------- final dot ----------
__global__ void k_out(const unsigned short* __restrict__ Y, const float* __restrict__ woutp,
                      const float* __restrict__ boutp, float* __restrict__ out) {
  __shared__ float w[128];
  const int tid = threadIdx.x;
  if (tid < 128) w[tid] = woutp[tid];
  __syncthreads();
  const int lane = tid & 63, wave = tid >> 6;
  const int sub = lane & 7, rloc = lane >> 3;
  const int row = blockIdx.x * 32 + wave * 8 + rloc;
  const unsigned short* yr = &Y[(size_t)row * 256 + sub * 16];
  short8 v0 = *(const short8*)yr;
  short8 v1 = *(const short8*)(yr + 8);
  float acc = 0.f;
#pragma unroll
  for (int j = 0; j < 8; j++) acc += bf2f((unsigned short)v0[j]) * w[sub * 16 + j];
#pragma unroll
  for (int j = 0; j < 8; j++) acc += bf2f((unsigned short)v1[j]) * w[sub * 16 + 8 + j];
  acc += __shfl_xor(acc, 1, 64);
  acc += __shfl_xor(acc, 2, 64);
  acc += __shfl_xor(acc, 4, 64);
  if (sub == 0) out[row] = acc + boutp[0];
}

extern "C" void kernel_launch(void* const* d_in, const int* in_sizes, int n_in,
                              void* d_out, int out_size, void* d_ws, size_t ws_size,
                              hipStream_t stream) {
  const int* x = (const int*)d_in[0];
  const float* tables = (const float*)d_in[1];
  const float* W0 = (const float*)d_in[2];
  const float* b0 = (const float*)d_in[3];
  const float* g0 = (const float*)d_in[4];
  const float* be0 = (const float*)d_in[5];
  const float* W1 = (const float*)d_in[6];
  const float* b1 = (const float*)d_in[7];
  const float* g1 = (const float*)d_in[8];
  const float* be1 = (const float*)d_in[9];
  const float* W2 = (const float*)d_in[10];
  const float* b2 = (const float*)d_in[11];
  const float* g2 = (const float*)d_in[12];
  const float* be2 = (const float*)d_in[13];
  const float* Wout = (const float*)d_in[14];
  const float* bout = (const float*)d_in[15];
  float* out = (float*)d_out;

  char* ws = (char*)d_ws;
  unsigned short* Y = (unsigned short*)ws;
  size_t off = (size_t)BR * 256 * 2;  // 134,217,728
  unsigned short* pW0 = (unsigned short*)(ws + off); off += (size_t)9 * 16 * 64 * 8 * 2;
  unsigned short* pW1 = (unsigned short*)(ws + off); off += (size_t)8 * 16 * 64 * 8 * 2;
  unsigned short* pW2 = (unsigned short*)(ws + off); off += (size_t)8 * 8 * 64 * 8 * 2;
  float* b1p = (float*)(ws + off); off += 1024;
  float* b2p = (float*)(ws + off); off += 512;
  float* woutp = (float*)(ws + off); off += 512;
  float* boutp = (float*)(ws + off); off += 256;
  float* stats = (float*)(ws + off); off += (size_t)NCOPY * 1280 * 4;
  unsigned short* tb = (unsigned short*)(ws + off); off += (size_t)17 * MAXR * 16 * 2;

  const int oS0 = 0, oQ0 = 256, oS1 = 512, oQ1 = 768, oS2 = 1024, oQ2 = 1152;

  k_prep0<<<64, 256, 0, stream>>>(W0, tables, pW0, tb, stats);
  k_gemm0<<<BR / 64, 256, 0, stream>>>(x, tb, pW0, b0, Y, stats, oS0, oQ0);
  k_fold<256, 256><<<16, 256, 0, stream>>>(stats, oS0, oQ0, g0, be0, W1, b1, pW1, b1p);
  k_gemm_mid<256, 4><<<BR / 64, 256, 0, stream>>>(Y, pW1, b1p, Y, stats, oS1, oQ1);
  k_fold<256, 128><<<16, 256, 0, stream>>>(stats, oS1, oQ1, g1, be1, W2, b2, pW2, b2p);
  k_gemm_mid<128, 2><<<BR / 64, 256, 0, stream>>>(Y, pW2, b2p, Y, stats, oS2, oQ2);
  k_foldout<<<1, 128, 0, stream>>>(stats, oS2, oQ2, g2, be2, Wout, bout, woutp, boutp);
  k_out<<<BR / 32, 256, 0, stream>>>(Y, woutp, boutp, out);
}

// Round 12
// 212.276 us; speedup vs baseline: 2.8889x; 1.0412x over previous
//
#include <hip/hip_runtime.h>
#include <stdint.h>

#define BR 262144
#define NTAB 17
#define MAXR 512
#define DIN 272
#define AS0 296   // LDS row stride (bf16) layer0 (K padded to 288); also C-restage stride
#define ASM 264   // LDS row stride (bf16) mid layers (K=256); also C-restage stride
#define NCOPY 32
#define BNEPS 1e-5f

typedef __attribute__((ext_vector_type(8))) short short8;
typedef __attribute__((ext_vector_type(4))) float f32x4;
typedef __attribute__((ext_vector_type(4))) unsigned short ushort4w;

__device__ __forceinline__ unsigned short f2bf(float f) {
  union { float f; unsigned u; } v; v.f = f;
  return (unsigned short)((v.u + 0x7FFFu + ((v.u >> 16) & 1u)) >> 16);
}
__device__ __forceinline__ float bf2f(unsigned short h) {
  union { unsigned u; float f; } v; v.u = ((unsigned)h) << 16;
  return v.f;
}

// ---------- prep: tables f32 -> bf16; pack W0 -> MFMA B-frags; zero stats ----------
__global__ void k_prep0(const float* __restrict__ W0, const float* __restrict__ tables,
                        unsigned short* __restrict__ pW0, unsigned short* __restrict__ tb,
                        float* __restrict__ stats) {
  int tid = blockIdx.x * blockDim.x + threadIdx.x;
  int nth = gridDim.x * blockDim.x;
  for (int i = tid; i < NCOPY * 1280; i += nth) stats[i] = 0.f;
  for (int e = tid; e < 17408; e += nth) {
    const float* src = tables + (size_t)e * 8;
    f32x4 v0 = ((const f32x4*)src)[0];
    f32x4 v1 = ((const f32x4*)src)[1];
    unsigned short tmp[8];
#pragma unroll
    for (int j = 0; j < 4; j++) { tmp[j] = f2bf(v0[j]); tmp[4 + j] = f2bf(v1[j]); }
    *(short8*)&tb[(size_t)e * 8] = *(short8*)tmp;
  }
  for (int e = tid; e < 9 * 16 * 64; e += nth) {
    int l = e & 63, f = e >> 6;
    int nf = f & 15, ks = f >> 4;
    int col = nf * 16 + (l & 15);
    int kb = ks * 32 + ((l >> 4) << 3);
    unsigned short tmp[8];
#pragma unroll
    for (int j = 0; j < 8; j++) {
      int k = kb + j;
      tmp[j] = f2bf(k < DIN ? W0[k * 256 + col] : 0.f);
    }
    *(short8*)&pW0[(size_t)e * 8] = *(short8*)tmp;
  }
}

// ---------- fold BN(layer l) into W(l+1) ----------
template <int KP, int NP>
__global__ void k_fold(const float* __restrict__ stats, int offSum, int offSq,
                       const float* __restrict__ g, const float* __restrict__ be,
                       const float* __restrict__ W, const float* __restrict__ b,
                       unsigned short* __restrict__ pW, float* __restrict__ bOut) {
  __shared__ float sa[KP], sc[KP];
  int tid = threadIdx.x;  // 256
  if (tid < KP) {
    float s = 0.f, q = 0.f;
    for (int c = 0; c < NCOPY; c++) {
      s += stats[c * 1280 + offSum + tid];
      q += stats[c * 1280 + offSq + tid];
    }
    float mu = s * (1.f / BR);
    float var = fmaxf(q * (1.f / BR) - mu * mu, 0.f);
    float a = g[tid] * rsqrtf(var + BNEPS);
    sa[tid] = a;
    sc[tid] = be[tid] - mu * a;
  }
  __syncthreads();
  const int NFT = NP / 16;
  const int ENT = (KP / 32) * NFT * 64;
  for (int e = blockIdx.x * blockDim.x + tid; e < ENT; e += gridDim.x * blockDim.x) {
    int l = e & 63, f = e >> 6;
    int nf = f % NFT, ks = f / NFT;
    int col = nf * 16 + (l & 15);
    int kb = ks * 32 + ((l >> 4) << 3);
    unsigned short tmp[8];
#pragma unroll
    for (int j = 0; j < 8; j++) {
      int k = kb + j;
      tmp[j] = f2bf(sa[k] * W[k * NP + col]);
    }
    *(short8*)&pW[(size_t)e * 8] = *(short8*)tmp;
  }
  if (blockIdx.x == 0 && tid < NP) {
    float s = b[tid];
    for (int k = 0; k < KP; k++) s += sc[k] * W[k * NP + tid];
    bOut[tid] = s;
  }
}

// ---------- fold BN(layer2) into Wout ----------
__global__ void k_foldout(const float* __restrict__ stats, int offSum, int offSq,
                          const float* __restrict__ g, const float* __restrict__ be,
                          const float* __restrict__ Wout, const float* __restrict__ bout,
                          float* __restrict__ woutp, float* __restrict__ boutp) {
  __shared__ float red[128];
  int tid = threadIdx.x;  // 128 threads
  float s = 0.f, q = 0.f;
  for (int c = 0; c < NCOPY; c++) {
    s += stats[c * 1280 + offSum + tid];
    q += stats[c * 1280 + offSq + tid];
  }
  float mu = s * (1.f / BR);
  float var = fmaxf(q * (1.f / BR) - mu * mu, 0.f);
  float a = g[tid] * rsqrtf(var + BNEPS);
  float c = be[tid] - mu * a;
  float w = Wout[tid];
  woutp[tid] = a * w;
  red[tid] = c * w;
  __syncthreads();
  for (int st = 64; st > 0; st >>= 1) {
    if (tid < st) red[tid] += red[tid + st];
    __syncthreads();
  }
  if (tid == 0) boutp[0] = red[0] + bout[0];
}

// ---------- shared GEMM body (R11-verified: stats in store phase) ----------
// swapped-operand MFMA acc frag: row = lane&15, col = (lane>>4)*4 + j  (verified R1-R11)
template <int KSTEPS, int N, int AST, int MF>
__device__ __forceinline__ void gemm_body(unsigned short* As, float* sbuf,
                                          const unsigned short* __restrict__ pW,
                                          const float* __restrict__ bias, unsigned short* __restrict__ Y,
                                          int brow, float* __restrict__ gsum, float* __restrict__ gsq) {
  const int tid = threadIdx.x;
  const int lane = tid & 63, wave = tid >> 6;
  constexpr int WC = N / 64;
  constexpr int CH = N / 8;
  const int wc = wave % WC, wr = wave / WC;
  const int wrow = wr * (MF * 16);
  const int wcolf = wc * 4;
  const int arow = lane & 15;
  const int koff = (lane >> 4) << 3;
  const int grp = lane >> 4;

  f32x4 zero4 = {0.f, 0.f, 0.f, 0.f};
  f32x4 acc[MF][4];
#pragma unroll
  for (int mf = 0; mf < MF; mf++)
#pragma unroll
    for (int nf = 0; nf < 4; nf++) acc[mf][nf] = zero4;

  short8 bcur[4], bnxt[4];
#pragma unroll
  for (int nf = 0; nf < 4; nf++)
    bcur[nf] = *(const short8*)&pW[(size_t)((wcolf + nf) * 64 + lane) * 8];

#pragma unroll
  for (int ks = 0; ks < KSTEPS; ks++) {
    if (ks + 1 < KSTEPS) {
#pragma unroll
      for (int nf = 0; nf < 4; nf++)
        bnxt[nf] = *(const short8*)&pW[(size_t)(((ks + 1) * (N / 16) + wcolf + nf) * 64 + lane) * 8];
    }
#pragma unroll
    for (int mf = 0; mf < MF; mf++) {
      short8 am = *(const short8*)&As[(wrow + mf * 16 + arow) * AST + ks * 32 + koff];
#pragma unroll
      for (int nf = 0; nf < 4; nf++)
        acc[mf][nf] = __builtin_amdgcn_mfma_f32_16x16x32_bf16(bcur[nf], am, acc[mf][nf], 0, 0, 0);
    }
#pragma unroll
    for (int nf = 0; nf < 4; nf++) bcur[nf] = bnxt[nf];
  }

  __syncthreads();  // all As reads done; reuse As as C restage buffer (stride AST)

  // epilogue: bias + relu + bf16 restage to LDS (no stats here)
#pragma unroll
  for (int nf = 0; nf < 4; nf++) {
    const int c0 = (wcolf + nf) * 16 + grp * 4;
    f32x4 bb = *(const f32x4*)&bias[c0];
#pragma unroll
    for (int mf = 0; mf < MF; mf++) {
      const int r = wrow + mf * 16 + arow;
      unsigned short o[4];
#pragma unroll
      for (int j = 0; j < 4; j++) o[j] = f2bf(fmaxf(acc[mf][nf][j] + bb[j], 0.f));
      *(ushort4w*)&As[r * AST + c0] = *(ushort4w*)o;
    }
  }
  __syncthreads();

  // store phase: coalesced row-major Y store (16B/lane) + per-thread column stats
  float s8[8] = {0.f, 0.f, 0.f, 0.f, 0.f, 0.f, 0.f, 0.f};
  float q8[8] = {0.f, 0.f, 0.f, 0.f, 0.f, 0.f, 0.f, 0.f};
  const int ch = tid % CH;
#pragma unroll
  for (int k = 0; k < (64 * CH) / 256; k++) {
    int i = tid + k * 256;
    int row = i / CH;
    short8 v = *(const short8*)&As[row * AST + ch * 8];
    *(short8*)&Y[(size_t)(brow + row) * 256 + ch * 8] = v;
#pragma unroll
    for (int j = 0; j < 8; j++) {
      float f = bf2f((unsigned short)v[j]);
      s8[j] += f;
      q8[j] += f * f;
    }
  }
#pragma unroll
  for (int d = CH; d < 64; d <<= 1) {
#pragma unroll
    for (int j = 0; j < 8; j++) {
      s8[j] += __shfl_xor(s8[j], d, 64);
      q8[j] += __shfl_xor(q8[j], d, 64);
    }
  }
  if (lane < CH) {
    float* dst = &sbuf[(wave * CH + lane) * 16];
#pragma unroll
    for (int j = 0; j < 8; j++) { dst[j] = s8[j]; dst[8 + j] = q8[j]; }
  }
  __syncthreads();
  for (int o = tid; o < CH * 16; o += 256) {
    int c = o >> 4, v = o & 15;
    float t = sbuf[(0 * CH + c) * 16 + v] + sbuf[(1 * CH + c) * 16 + v] +
              sbuf[(2 * CH + c) * 16 + v] + sbuf[(3 * CH + c) * 16 + v];
    int col = c * 8 + (v & 7);
    atomicAdd((v < 8 ? gsum : gsq) + col, t);
  }
}

// ---------- layer 0: gather (idx-prefetch, 1 idx per (row,table)) + GEMM ----------
__global__ __launch_bounds__(256, 3) void k_gemm0(const int* __restrict__ x, const unsigned short* __restrict__ tb,
                        const unsigned short* __restrict__ pW, const float* __restrict__ bias,
                        unsigned short* __restrict__ Y, float* __restrict__ stats, int offSum, int offSq) {
  __shared__ unsigned short As[64 * AS0];
  __shared__ float sbuf[4 * 32 * 16];
  const int tid = threadIdx.x;
  const int brow = blockIdx.x * 64;

  // phase 1: issue all idx loads (registers, static indices)
  int idxr[5];
#pragma unroll
  for (int j = 0; j < 5; j++) {
    int task = tid + j * 256;          // task = r*17 + t; 1088 tasks
    if (task < 64 * NTAB) {
      int r = task / NTAB;
      int t = task - r * NTAB;
      idxr[j] = x[(brow + r) * NTAB + t];
    }
  }
  // phase 2: zero K padding cols 272..295 (hides idx latency)
  short8 z8 = {0, 0, 0, 0, 0, 0, 0, 0};
  for (int t = tid; t < 64; t += 256) {
    *(short8*)&As[t * AS0 + 272] = z8;
    *(short8*)&As[t * AS0 + 280] = z8;
    *(short8*)&As[t * AS0 + 288] = z8;
  }
  // phase 3: gather 32B per task (2x16B loads + 2x16B LDS writes)
#pragma unroll
  for (int j = 0; j < 5; j++) {
    int task = tid + j * 256;
    if (task < 64 * NTAB) {
      int r = task / NTAB;
      int t = task - r * NTAB;
      const unsigned short* src = &tb[((size_t)(t * MAXR) + idxr[j]) * 16];
      short8 v0 = *(const short8*)src;
      short8 v1 = *(const short8*)(src + 8);
      unsigned base = r * AS0 + t * 16;
      *(short8*)&As[base] = v0;
      *(short8*)&As[base + 8] = v1;
    }
  }
  __syncthreads();
  float* gsum = stats + (size_t)(blockIdx.x & (NCOPY - 1)) * 1280 + offSum;
  float* gsq  = stats + (size_t)(blockIdx.x & (NCOPY - 1)) * 1280 + offSq;
  gemm_body<9, 256, AS0, 4>(As, sbuf, pW, bias, Y, brow, gsum, gsq);
}

// ---------- mid layers (R11 exact) ----------
template <int N, int MF>
__global__ __launch_bounds__(256, 3) void k_gemm_mid(const unsigned short* __restrict__ Yin,
                           const unsigned short* __restrict__ pW, const float* __restrict__ bias,
                           unsigned short* __restrict__ Y, float* __restrict__ stats, int offSum, int offSq) {
  __shared__ unsigned short As[64 * ASM];
  __shared__ float sbuf[4 * (N / 8) * 16];
  const int tid = threadIdx.x;
  const int brow = blockIdx.x * 64;
  for (int i = tid; i < 64 * 32; i += 256) {
    int row = i >> 5, c16 = i & 31;
    short8 v = *(const short8*)&Yin[((size_t)(brow + row)) * 256 + c16 * 8];
    *(short8*)&As[row * ASM + c16 * 8] = v;
  }
  __syncthreads();
  float* gsum = stats + (size_t)(blockIdx.x & (NCOPY - 1)) * 1280 + offSum;
  float* gsq  = stats + (size_t)(blockIdx.x & (NCOPY - 1)) * 1280 + offSq;
  gemm_body<8, N, ASM, MF>(As, sbuf, pW, bias, Y, brow, gsum, gsq);
}

// ---------- final dot (R11 exact) ----------
__global__ void k_out(const unsigned short* __restrict__ Y, const float* __restrict__ woutp,
                      const float* __restrict__ boutp, float* __restrict__ out) {
  __shared__ float w[128];
  const int tid = threadIdx.x;
  if (tid < 128) w[tid] = woutp[tid];
  __syncthreads();
  const int lane = tid & 63, wave = tid >> 6;
  const int sub = lane & 7, rloc = lane >> 3;
  const int row = blockIdx.x * 32 + wave * 8 + rloc;
  const unsigned short* yr = &Y[(size_t)row * 256 + sub * 16];
  short8 v0 = *(const short8*)yr;
  short8 v1 = *(const short8*)(yr + 8);
  float acc = 0.f;
#pragma unroll
  for (int j = 0; j < 8; j++) acc += bf2f((unsigned short)v0[j]) * w[sub * 16 + j];
#pragma unroll
  for (int j = 0; j < 8; j++) acc += bf2f((unsigned short)v1[j]) * w[sub * 16 + 8 + j];
  acc += __shfl_xor(acc, 1, 64);
  acc += __shfl_xor(acc, 2, 64);
  acc += __shfl_xor(acc, 4, 64);
  if (sub == 0) out[row] = acc + boutp[0];
}

extern "C" void kernel_launch(void* const* d_in, const int* in_sizes, int n_in,
                              void* d_out, int out_size, void* d_ws, size_t ws_size,
                              hipStream_t stream) {
  const int* x = (const int*)d_in[0];
  const float* tables = (const float*)d_in[1];
  const float* W0 = (const float*)d_in[2];
  const float* b0 = (const float*)d_in[3];
  const float* g0 = (const float*)d_in[4];
  const float* be0 = (const float*)d_in[5];
  const float* W1 = (const float*)d_in[6];
  const float* b1 = (const float*)d_in[7];
  const float* g1 = (const float*)d_in[8];
  const float* be1 = (const float*)d_in[9];
  const float* W2 = (const float*)d_in[10];
  const float* b2 = (const float*)d_in[11];
  const float* g2 = (const float*)d_in[12];
  const float* be2 = (const float*)d_in[13];
  const float* Wout = (const float*)d_in[14];
  const float* bout = (const float*)d_in[15];
  float* out = (float*)d_out;

  char* ws = (char*)d_ws;
  unsigned short* Y = (unsigned short*)ws;
  size_t off = (size_t)BR * 256 * 2;  // 134,217,728
  unsigned short* pW0 = (unsigned short*)(ws + off); off += (size_t)9 * 16 * 64 * 8 * 2;
  unsigned short* pW1 = (unsigned short*)(ws + off); off += (size_t)8 * 16 * 64 * 8 * 2;
  unsigned short* pW2 = (unsigned short*)(ws + off); off += (size_t)8 * 8 * 64 * 8 * 2;
  float* b1p = (float*)(ws + off); off += 1024;
  float* b2p = (float*)(ws + off); off += 512;
  float* woutp = (float*)(ws + off); off += 512;
  float* boutp = (float*)(ws + off); off += 256;
  float* stats = (float*)(ws + off); off += (size_t)NCOPY * 1280 * 4;
  unsigned short* tb = (unsigned short*)(ws + off); off += (size_t)17 * MAXR * 16 * 2;

  const int oS0 = 0, oQ0 = 256, oS1 = 512, oQ1 = 768, oS2 = 1024, oQ2 = 1152;

  k_prep0<<<64, 256, 0, stream>>>(W0, tables, pW0, tb, stats);
  k_gemm0<<<BR / 64, 256, 0, stream>>>(x, tb, pW0, b0, Y, stats, oS0, oQ0);
  k_fold<256, 256><<<16, 256, 0, stream>>>(stats, oS0, oQ0, g0, be0, W1, b1, pW1, b1p);
  k_gemm_mid<256, 4><<<BR / 64, 256, 0, stream>>>(Y, pW1, b1p, Y, stats, oS1, oQ1);
  k_fold<256, 128><<<16, 256, 0, stream>>>(stats, oS1, oQ1, g1, be1, W2, b2, pW2, b2p);
  k_gemm_mid<128, 2><<<BR / 64, 256, 0, stream>>>(Y, pW2, b2p, Y, stats, oS2, oQ2);
  k_foldout<<<1, 128, 0, stream>>>(stats, oS2, oQ2, g2, be2, Wout, bout, woutp, boutp);
  k_out<<<BR / 32, 256, 0, stream>>>(Y, woutp, boutp, out);
}